// Round 7
// baseline (668.933 us; speedup 1.0000x reference)
//
#include <hip/hip_runtime.h>

// ---------------- constants ----------------
#define BB 2
#define LL 2048
#define DM 512
#define NH 8
#define DH 64
#define DFF 2048
#define UU 409          // max(1, 2048/5)
#define ROWS (BB*LL)    // 4096
#define X_ELEMS 2097152
#define NCHUNK 8        // K-split chunks (256 keys each) in flash attention

typedef unsigned short u16;
typedef __attribute__((ext_vector_type(8))) short short8;
typedef __attribute__((ext_vector_type(4))) float floatx4;

// ---- static scratch arena (~153 MB). No d_ws dependence. ----
#define G_TOTAL 38200000
__device__ float g_buf[G_TOTAL];
__device__ int   g_isbf16;

// arena layout (float offsets)
#define A_Q     10495488  // fp32 (A_K, A_V consecutive — SEC writes rely on this)
#define A_K     12592640
#define A_V     14689792
#define A_MKN   25175552
#define A_MS    25176576
#define A_RANK  25209344  // [16][2048] int
#define A_PARTK 25242112
#define A_LIST  25274880
#define A_PO    25281536  // [16 bh][8 chunk][512 slot][64] fp32
#define A_PML   29475840  // [16][8][512][2] fp32 -> end 29606912
#define A_CTXF  16786944
// u16 offsets
#define XN_H    16796672
#define XN_L    18893824
#define CTX_H   33573888
#define CTX_L   35671040
#define ENC_H   37768192
#define ENC_L   39865344
#define AH_H    41962496
// pre-converted K/V for attention (bf16 hi/lo, V transposed per bh):
// float 29606912 -> u16 59213824; 4 x 2,097,152 u16 -> end 67602432 < WT_SAQKV
#define KH16    59213824  // [bh][2048][64]
#define KL16    61310976
#define VTH16   63408128  // [bh][64][2048]
#define VTL16   65505280
#define WT_SAQKV 67864576   // N=1536 K=512: hi 786432, lo +786432
#define WT_SAO   69437440   // N=512: hi 262144, lo +262144
#define WT_CAQ   69961728
#define WT_CAKV  70486016   // N=1024 K=512 combined: hi 524288, lo +524288
#define WT_CAO   71534592
#define WT_W1    72058880   // N=2048 K=512
#define WT_W2    74156032   // N=512 K=2048
// end u16 = 76,253,184 = 38,126,592 floats < G_TOTAL ✓

__constant__ int c_end[28] = {
    2097152, 4194304, 4456448, 4456960, 4719104, 4719616, 4981760, 4982272,
    5244416, 5244928, 5507072, 5507584, 5769728, 5770240, 6032384, 6032896,
    6295040, 6295552, 7344128, 7346176, 8394752, 8395264, 8395776, 8396288,
    8396800, 8397312, 8397824, 8398336
};
__constant__ int sm_idx[16] = {3,5,7,9,11,13,15,17,19,21,22,23,24,25,26,27};
__constant__ int sm_cum[16] = {64,128,192,256,320,384,448,512,768,832,896,960,1024,1088,1152,1216};
#define XG 262144
#define EG 262144
#define SG 1216

__device__ __forceinline__ float bf2f(u16 x) {
    union { unsigned int u; float f; } c; c.u = ((unsigned int)x) << 16; return c.f;
}
__device__ __forceinline__ u16 f2bf(float f) {
    union { float f; unsigned int u; } c; c.f = f;
    unsigned int u = c.u;
    return (u16)((u + 0x7FFFu + ((u >> 16) & 1u)) >> 16);
}
// pack two f32 -> bf16 pair (low = a, high = b), RNE
__device__ __forceinline__ unsigned cvtpk_bf16(float a, float b) {
    unsigned r;
    asm("v_cvt_pk_bf16_f32 %0, %1, %2" : "=v"(r) : "v"(a), "v"(b));
    return r;
}

struct P28 { const void* p[28]; };
struct I3 { int v[3]; };

// ---------------- prep_all: weight transpose (blocks 0..1023) + canonicalize (1024..3071) ----------------
__constant__ int tj[10][6] = {
    {2,  WT_SAQKV, 0,    512,  786432, 8},   // sa_wq
    {4,  WT_SAQKV, 512,  512,  786432, 8},   // sa_wk
    {6,  WT_SAQKV, 1024, 512,  786432, 8},   // sa_wv
    {8,  WT_SAO,   0,    512,  262144, 8},   // sa_wo
    {10, WT_CAQ,   0,    512,  262144, 8},   // ca_wq
    {12, WT_CAKV,  0,    512,  524288, 8},   // ca_wk  (combined N=1024 slot)
    {14, WT_CAKV,  512,  512,  524288, 8},   // ca_wv
    {16, WT_CAO,   0,    512,  262144, 8},   // ca_wo
    {18, WT_W1,    0,    512, 1048576, 32},  // ff_w1
    {20, WT_W2,    0,   2048, 1048576, 8},   // ff_w2
};
__constant__ int tcum[10] = {64, 128, 192, 256, 320, 384, 448, 512, 768, 1024};
__global__ void prep_all(P28 ps) {
    const int f = (((const u16*)ps.p[22])[0] == 0x3F80u) ? 1 : 0;
    if (blockIdx.x == 0 && threadIdx.x == 0) g_isbf16 = f;
    u16* gb16 = (u16*)g_buf;
    if (blockIdx.x < 1024) {
        int bid = blockIdx.x;
        int j = 0;
        while (bid >= tcum[j]) j++;
        int t = bid - (j ? tcum[j - 1] : 0);
        int widx = tj[j][0], wt = tj[j][1], col0 = tj[j][2];
        int K = tj[j][3], lo = tj[j][4], txn = tj[j][5];
        int Nsrc = txn * 64;
        int n0 = (t % txn) * 64, k0 = (t / txn) * 64;
        __shared__ float tb[64][65];
        int c = threadIdx.x & 63, r0 = threadIdx.x >> 6;
        const void* W = ps.p[widx];
        u16* WTh = gb16 + wt;
        for (int i = 0; i < 16; i++) {
            int r = r0 + 4 * i;
            size_t src = (size_t)(k0 + r) * Nsrc + n0 + c;
            tb[r][c] = f ? bf2f(((const u16*)W)[src]) : ((const float*)W)[src];
        }
        __syncthreads();
        for (int i = 0; i < 16; i++) {
            int r = r0 + 4 * i;
            float v = tb[c][r];
            u16 hi = f2bf(v);
            size_t o = (size_t)(col0 + n0 + r) * K + k0 + c;
            WTh[o] = hi;
            WTh[lo + o] = f2bf(v - bf2f(hi));
        }
        return;
    }
    int stride = 2048 * blockDim.x;
    for (int g = (blockIdx.x - 1024) * blockDim.x + threadIdx.x; g < XG + EG + SG; g += stride) {
        if (g < XG) {
            int e = g * 8;
            if (f) {
                uint4 raw = ((const uint4*)ps.p[0])[g];
                const u16* rr = (const u16*)&raw;
                float v[8] __attribute__((aligned(16)));
#pragma unroll
                for (int i = 0; i < 8; i++) v[i] = bf2f(rr[i]);
                *(float4*)(g_buf + e) = ((const float4*)v)[0];
                *(float4*)(g_buf + e + 4) = ((const float4*)v)[1];
            } else {
                *(uint4*)(g_buf + e)     = ((const uint4*)ps.p[0])[g * 2];
                *(uint4*)(g_buf + e + 4) = ((const uint4*)ps.p[0])[g * 2 + 1];
            }
        } else if (g < XG + EG) {
            int gl = g - XG;
            int e = gl * 8;
            float v[8] __attribute__((aligned(16)));
            if (f) {
                uint4 raw = ((const uint4*)ps.p[1])[gl];
                const u16* rr = (const u16*)&raw;
#pragma unroll
                for (int i = 0; i < 8; i++) v[i] = bf2f(rr[i]);
            } else {
                *(float4*)(v)     = ((const float4*)ps.p[1])[gl * 2];
                *(float4*)(v + 4) = ((const float4*)ps.p[1])[gl * 2 + 1];
            }
            u16 hh[8] __attribute__((aligned(16)));
            u16 lo[8] __attribute__((aligned(16)));
#pragma unroll
            for (int i = 0; i < 8; i++) { u16 hi = f2bf(v[i]); hh[i] = hi; lo[i] = f2bf(v[i] - bf2f(hi)); }
            *(uint4*)(&gb16[ENC_H + e]) = *(const uint4*)hh;
            *(uint4*)(&gb16[ENC_L + e]) = *(const uint4*)lo;
        } else {
            int t = g - XG - EG;
            int si = 0;
            while (t >= sm_cum[si]) si++;
            int s = sm_idx[si];
            int gl = t - (si ? sm_cum[si - 1] : 0);
            int e = gl * 8;
            float* dst = g_buf + c_end[s - 1] + e;
            if (f) {
                uint4 raw = *(const uint4*)((const u16*)ps.p[s] + e);
                const u16* rr = (const u16*)&raw;
#pragma unroll
                for (int i = 0; i < 8; i++) dst[i] = bf2f(rr[i]);
            } else {
                *(uint4*)(dst)     = *(const uint4*)((const float*)ps.p[s] + e);
                *(uint4*)(dst + 4) = *(const uint4*)((const float*)ps.p[s] + e + 4);
            }
        }
    }
}

// ---------------- layernorm: fp32 in, bf16 hi/lo out ----------------
__global__ void lnorm_k(int x_off, int g_off, int b_off, int yh_u16, int yl_u16) {
    int row = blockIdx.x;
    int tid = threadIdx.x;
    const float* x = g_buf + x_off + (size_t)row * DM;
    float a = x[tid], c = x[tid + 256];
    float s1 = a + c, s2 = a * a + c * c;
    for (int o = 32; o > 0; o >>= 1) { s1 += __shfl_xor(s1, o); s2 += __shfl_xor(s2, o); }
    __shared__ float r1[4], r2[4];
    int wave = tid >> 6, lane = tid & 63;
    if (lane == 0) { r1[wave] = s1; r2[wave] = s2; }
    __syncthreads();
    s1 = r1[0] + r1[1] + r1[2] + r1[3];
    s2 = r2[0] + r2[1] + r2[2] + r2[3];
    float mean = s1 * (1.0f / DM);
    float var  = s2 * (1.0f / DM) - mean * mean;
    float rstd = rsqrtf(var + 1e-5f);
    const float* gg = g_buf + g_off;
    const float* bb = g_buf + b_off;
    u16* yh = ((u16*)g_buf) + yh_u16 + (size_t)row * DM;
    u16* yl = ((u16*)g_buf) + yl_u16 + (size_t)row * DM;
    float v1 = (a - mean) * rstd * gg[tid]       + bb[tid];
    float v2 = (c - mean) * rstd * gg[tid + 256] + bb[tid + 256];
    u16 h1 = f2bf(v1), h2 = f2bf(v2);
    yh[tid] = h1;       yl[tid] = f2bf(v1 - bf2f(h1));
    yh[tid + 256] = h2; yl[tid + 256] = f2bf(v2 - bf2f(h2));
}

// ---------------- MFMA bf16 GEMM (XCD = mt%8) + T14 issue-early/commit-late staging ----------------
// Loads for tile k+1 are issued into registers immediately after committing tile k to LDS,
// so global latency hides under tile k's ds_read+MFMA phase. MFMA order unchanged.
template<int WM, bool SPLIT, bool SEC, bool RELU, bool RESID, bool FINAL, bool OUTH>
__global__ void mgemm_k(I3 a_offs, I3 splt, I3 alz, int wt_u16_off, I3 boffs, int resid_off,
                        int out_off, void* __restrict__ dext, int M, int N, int K) {
    constexpr int BT_M = WM * 32;
    constexpr int A4 = BT_M * 4;
    constexpr int NA = (A4 + 255) / 256;
    __shared__ u16 Ash[BT_M * 40];
    __shared__ u16 Asl[SPLIT ? BT_M * 40 : 8];
    __shared__ u16 Bsh[128 * 40];
    __shared__ u16 Bsl[SPLIT ? 128 * 40 : 8];
    int ntb = blockIdx.y;
    int sec_blk = SEC ? ((ntb * 128) >> 9) : 0;
    const u16* Ah = ((const u16*)g_buf) + a_offs.v[sec_blk];
    const u16* Al = Ah + (size_t)M * K;
    const u16* WTh = ((const u16*)g_buf) + wt_u16_off;
    const u16* WTl = WTh + (size_t)N * K;
    const int isbf = g_isbf16;
    const bool use_al = SPLIT && splt.v[sec_blk] && !(alz.v[sec_blk] && isbf);
    const bool use_bl = SPLIT && splt.v[sec_blk] && !isbf;
    int tid = threadIdx.x;
    int lane = tid & 63, wid = tid >> 6;
    int wm = wid >> 1, wn = wid & 1;
    int quad = lane >> 4, l15 = lane & 15;
    int m0 = blockIdx.x * BT_M, n0 = ntb * 128;

    uint4 pA[NA], pAl[NA], pB[2], pBl[2];
    auto issue = [&](int k0) {
#pragma unroll
        for (int i = 0; i < NA; i++) {
            int idx8 = tid + 256 * i;
            if (A4 % 256 == 0 || idx8 < A4) {
                int r = idx8 >> 2, c8 = (idx8 & 3) * 8;
                pA[i] = *(const uint4*)(Ah + (size_t)(m0 + r) * K + k0 + c8);
                if (SPLIT && use_al)
                    pAl[i] = *(const uint4*)(Al + (size_t)(m0 + r) * K + k0 + c8);
            }
        }
#pragma unroll
        for (int i = 0; i < 2; i++) {
            int idx8 = tid + 256 * i;
            int r = idx8 >> 2, c8 = (idx8 & 3) * 8;
            pB[i] = *(const uint4*)(WTh + (size_t)(n0 + r) * K + k0 + c8);
            if (SPLIT && use_bl)
                pBl[i] = *(const uint4*)(WTl + (size_t)(n0 + r) * K + k0 + c8);
        }
    };
    auto commit = [&]() {
#pragma unroll
        for (int i = 0; i < NA; i++) {
            int idx8 = tid + 256 * i;
            if (A4 % 256 == 0 || idx8 < A4) {
                int r = idx8 >> 2, c8 = (idx8 & 3) * 8;
                *(uint4*)(&Ash[r * 40 + c8]) = pA[i];
                if (SPLIT && use_al) *(uint4*)(&Asl[r * 40 + c8]) = pAl[i];
            }
        }
#pragma unroll
        for (int i = 0; i < 2; i++) {
            int idx8 = tid + 256 * i;
            int r = idx8 >> 2, c8 = (idx8 & 3) * 8;
            *(uint4*)(&Bsh[r * 40 + c8]) = pB[i];
            if (SPLIT && use_bl) *(uint4*)(&Bsl[r * 40 + c8]) = pBl[i];
        }
    };

    floatx4 acc[WM][4];
#pragma unroll
    for (int i = 0; i < WM; i++)
#pragma unroll
        for (int j = 0; j < 4; j++) acc[i][j] = (floatx4){0.f, 0.f, 0.f, 0.f};

    issue(0);
    for (int k0 = 0; k0 < K; k0 += 32) {
        __syncthreads();                 // prev tile's readers done
        commit();
        if (k0 + 32 < K) issue(k0 + 32); // next-tile loads fly during this tile's MFMA
        __syncthreads();                 // commit visible
        short8 ah[WM], bh[4], al[WM], bl[4];
#pragma unroll
        for (int i = 0; i < WM; i++) {
            int ro = (wm * WM * 16 + i * 16 + l15) * 40 + quad * 8;
            ah[i] = *(const short8*)(&Ash[ro]);
            if (SPLIT && use_al) al[i] = *(const short8*)(&Asl[ro]);
        }
#pragma unroll
        for (int j = 0; j < 4; j++) {
            int ro = (wn * 64 + j * 16 + l15) * 40 + quad * 8;
            bh[j] = *(const short8*)(&Bsh[ro]);
            if (SPLIT && use_bl) bl[j] = *(const short8*)(&Bsl[ro]);
        }
#pragma unroll
        for (int i = 0; i < WM; i++)
#pragma unroll
            for (int j = 0; j < 4; j++) {
                acc[i][j] = __builtin_amdgcn_mfma_f32_16x16x32_bf16(ah[i], bh[j], acc[i][j], 0, 0, 0);
                if constexpr (SPLIT) {
                    if (use_bl)
                        acc[i][j] = __builtin_amdgcn_mfma_f32_16x16x32_bf16(ah[i], bl[j], acc[i][j], 0, 0, 0);
                    if (use_al)
                        acc[i][j] = __builtin_amdgcn_mfma_f32_16x16x32_bf16(al[i], bh[j], acc[i][j], 0, 0, 0);
                }
            }
    }
#pragma unroll
    for (int i = 0; i < WM; i++)
#pragma unroll
        for (int j = 0; j < 4; j++)
#pragma unroll
            for (int r = 0; r < 4; r++) {
                int row = m0 + wm * WM * 16 + i * 16 + quad * 4 + r;
                int col = n0 + wn * 64 + j * 16 + l15;
                int sec = SEC ? (col >> 9) : 0;
                int ci  = SEC ? (col & 511) : col;
                float v = acc[i][j][r] + g_buf[boffs.v[sec] + ci];
                if (RELU) v = fmaxf(v, 0.f);
                if (RESID) v += g_buf[resid_off + (size_t)row * N + col];
                if (FINAL) {
                    if (g_isbf16) ((u16*)dext)[(size_t)row * N + col] = f2bf(v);
                    else          ((float*)dext)[(size_t)row * N + col] = v;
                } else if (OUTH) {
                    ((u16*)g_buf)[out_off + (size_t)row * N + col] = f2bf(v);
                } else if (SEC) {
                    g_buf[out_off + ((size_t)sec * ROWS + row) * 512 + ci] = v;
                } else {
                    g_buf[out_off + (size_t)row * N + col] = v;
                }
            }
}

// ---------------- skinny-N GEMM v3: single-wave 16x64 tile, 4-deep register pipeline ----------------
// Round-6 post-mortem: VGPR=64 (no min-waves arg -> regalloc targeted 8 waves/EU and
// collapsed the 4 buffer sets). Fix: __launch_bounds__(64, 2) -> 256-VGPR budget; grid is
// 8 blocks/CU = 2 waves/SIMD anyway. Verification signal: VGPR_Count >= ~110.
template<bool SPLIT, bool RESID, bool FINAL>
__global__ __launch_bounds__(64, 2) void sgemm_k(int a_off, int sp, int alz, int wt_u16_off,
        int b_off, int resid_off, int out_off, void* __restrict__ dext, int M, int N, int K) {
    const u16* gb = (const u16*)g_buf;
    const u16* Ah = gb + a_off;
    const u16* Alp = Ah + (size_t)M * K;
    const u16* Bh = gb + wt_u16_off;
    const u16* Blp = Bh + (size_t)N * K;
    const int isbf = g_isbf16;
    const bool ual = SPLIT && sp && !(alz && isbf);
    const bool ubl = SPLIT && sp && !isbf;
    int mtiles = M >> 4;
    int bid = blockIdx.x;
    int mt = bid % mtiles, nt = bid / mtiles;
    int n0 = nt * 64, m0 = mt * 16;
    int lane = threadIdx.x;
    int quad = lane >> 4, l15 = lane & 15;
    const u16* ap  = Ah  + (size_t)(m0 + l15) * K + quad * 8;
    const u16* alq = Alp + (size_t)(m0 + l15) * K + quad * 8;
    const u16* bp  = Bh  + (size_t)(n0 + l15) * K + quad * 8;
    const u16* blq = Blp + (size_t)(n0 + l15) * K + quad * 8;
    floatx4 acc[4];
#pragma unroll
    for (int j = 0; j < 4; j++) acc[j] = (floatx4){0.f, 0.f, 0.f, 0.f};

    short8 AH0, AH1, AH2, AH3, AL0, AL1, AL2, AL3;
    short8 BH0[4], BH1[4], BH2[4], BH3[4], BL0[4], BL1[4], BL2[4], BL3[4];

#define SLOAD(P, KK) do { int kk_ = (KK); \
        AH##P = *(const short8*)(ap + kk_); \
        if (ual) AL##P = *(const short8*)(alq + kk_); \
        _Pragma("unroll") \
        for (int j = 0; j < 4; j++) { \
            BH##P[j] = *(const short8*)(bp + (size_t)j * 16 * K + kk_); \
            if (ubl) BL##P[j] = *(const short8*)(blq + (size_t)j * 16 * K + kk_); \
        } } while (0)

#define SMFMA(P) do { \
        _Pragma("unroll") \
        for (int j = 0; j < 4; j++) { \
            acc[j] = __builtin_amdgcn_mfma_f32_16x16x32_bf16(AH##P, BH##P[j], acc[j], 0, 0, 0); \
            if (SPLIT) { \
                if (ubl) acc[j] = __builtin_amdgcn_mfma_f32_16x16x32_bf16(AH##P, BL##P[j], acc[j], 0, 0, 0); \
                if (ual) acc[j] = __builtin_amdgcn_mfma_f32_16x16x32_bf16(AL##P, BH##P[j], acc[j], 0, 0, 0); \
            } \
        } } while (0)

    SLOAD(0, 0); SLOAD(1, 32); SLOAD(2, 64); SLOAD(3, 96);
    int k0 = 0;
    for (; k0 + 128 < K; k0 += 128) {           // K in {512, 2048}: multiple of 128
        SMFMA(0); SLOAD(0, k0 + 128);
        SMFMA(1); SLOAD(1, k0 + 160);
        SMFMA(2); SLOAD(2, k0 + 192);
        SMFMA(3); SLOAD(3, k0 + 224);
    }
    SMFMA(0); SMFMA(1); SMFMA(2); SMFMA(3);     // drain: k0 == K-128
#undef SLOAD
#undef SMFMA

    const float* bias = g_buf + b_off;
#pragma unroll
    for (int j = 0; j < 4; j++)
#pragma unroll
        for (int r = 0; r < 4; r++) {
            int row = m0 + quad * 4 + r;
            int col = n0 + j * 16 + l15;
            float v = acc[j][r] + bias[col];
            if (RESID) v += g_buf[resid_off + (size_t)row * N + col];
            if (FINAL) {
                if (isbf) ((u16*)dext)[(size_t)row * N + col] = f2bf(v);
                else      ((float*)dext)[(size_t)row * N + col] = v;
            } else {
                g_buf[out_off + (size_t)row * N + col] = v;
            }
        }
}

// ---------------- mean of normalized K rows: phase 1 ----------------
__global__ void meankn_p1(int k_off, int part_off) {
    int bh = blockIdx.x >> 5, chunk = blockIdx.x & 31;
    int b = bh >> 3, h = bh & 7;
    int wave = threadIdx.x >> 6, lane = threadIdx.x & 63;
    const float* base = g_buf + k_off + (size_t)b * LL * DM + (size_t)h * DH + lane;
    float acc = 0.f;
    for (int t = 0; t < 16; t++) {
        int j = chunk * 64 + wave * 16 + t;
        float kv = base[(size_t)j * DM];
        float s = kv * kv;
        for (int o = 32; o > 0; o >>= 1) s += __shfl_xor(s, o);
        acc += kv / sqrtf(fmaxf(s, 1e-30f));
    }
    __shared__ float red[4][64];
    red[wave][lane] = acc;
    __syncthreads();
    if (threadIdx.x < 64)
        g_buf[part_off + (size_t)blockIdx.x * 64 + threadIdx.x] =
            red[0][threadIdx.x] + red[1][threadIdx.x] + red[2][threadIdx.x] + red[3][threadIdx.x];
}

// ---------------- mean score (fused p2): grid (64 chunks, 16 bh), 32 rows/block ----------------
__global__ void mscore_k(int q_off, int part_off, int ms_off) {
    int bh = blockIdx.y, b = bh >> 3, h = bh & 7;
    int tid = threadIdx.x;
    __shared__ float mk[64];
    if (tid < 64) {
        float s = 0.f;
        for (int c = 0; c < 32; c++) s += g_buf[part_off + (size_t)(bh * 32 + c) * 64 + tid];
        mk[tid] = s * (1.0f / LL);
    }
    __syncthreads();
    int w = tid >> 6, lane = tid & 63;
    float m = mk[lane];
#pragma unroll
    for (int it = 0; it < 8; it++) {
        int row = blockIdx.x * 32 + it * 4 + w;
        float qv = g_buf[q_off + ((size_t)b * LL + row) * DM + h * DH + lane];
        float s = qv * qv, d = qv * m;
        for (int o = 32; o > 0; o >>= 1) { s += __shfl_xor(s, o); d += __shfl_xor(d, o); }
        if (lane == 0) g_buf[ms_off + bh * LL + row] = d / sqrtf(fmaxf(s, 1e-30f));
    }
}

// ---------------- top-u: rank-count -> score-ordered list + rank map ----------------
__global__ void topsel_k(int ms_off, int list_off, int rank_off, int u) {
    __shared__ float s[LL];
    int bh = blockIdx.y, chunk = blockIdx.x;
    for (int i = threadIdx.x; i < LL; i += 256) s[i] = g_buf[ms_off + bh * LL + i];
    __syncthreads();
    int il = threadIdx.x >> 2;
    int i = chunk * 64 + il;
    int jq = threadIdx.x & 3;
    float si = s[i];
    int cnt = 0;
    for (int t = 0; t < 512; t++) {
        int j = jq * 512 + t;
        float sj = s[j];
        cnt += (sj > si) || (sj == si && j < i);
    }
    cnt += __shfl_xor(cnt, 1);
    cnt += __shfl_xor(cnt, 2);
    if (jq == 0) {
        int* list = (int*)(g_buf + list_off);
        int* rank = (int*)(g_buf + rank_off);
        if (cnt < u) { list[bh * 416 + cnt] = i; rank[bh * LL + i] = cnt; }
        else rank[bh * LL + i] = -1;
    }
}

// ---------------- kvprep: fp32 K/V -> bf16 hi/lo, V transposed per bh ----------------
template<bool LO>
__global__ void kvprep_k(int k_off, int v_off) {
    int bh = blockIdx.y, b = bh >> 3, h = bh & 7;
    int tok0 = blockIdx.x * 64;
    int tid = threadIdx.x;
    __shared__ float vt[64][68];
    u16* gb16 = (u16*)g_buf;
    int tok = tid >> 2, dq = (tid & 3) * 16;
    const float* kp = g_buf + k_off + ((size_t)(b * LL + tok0 + tok)) * DM + h * DH + dq;
    const float* vp = g_buf + v_off + ((size_t)(b * LL + tok0 + tok)) * DM + h * DH + dq;
    float kv[16] __attribute__((aligned(16)));
#pragma unroll
    for (int i = 0; i < 4; i++) *(float4*)(kv + 4 * i) = *(const float4*)(kp + 4 * i);
    u16 hh[16] __attribute__((aligned(16)));
    u16 lo[16] __attribute__((aligned(16)));
#pragma unroll
    for (int i = 0; i < 16; i++) { hh[i] = f2bf(kv[i]); if (LO) lo[i] = f2bf(kv[i] - bf2f(hh[i])); }
    size_t ko = ((size_t)(bh * LL + tok0 + tok)) * DH + dq;
    *(uint4*)(gb16 + KH16 + ko)     = ((const uint4*)hh)[0];
    *(uint4*)(gb16 + KH16 + ko + 8) = ((const uint4*)hh)[1];
    if (LO) {
        *(uint4*)(gb16 + KL16 + ko)     = ((const uint4*)lo)[0];
        *(uint4*)(gb16 + KL16 + ko + 8) = ((const uint4*)lo)[1];
    }
#pragma unroll
    for (int i = 0; i < 4; i++) *(float4*)(&vt[tok][dq + 4 * i]) = *(const float4*)(vp + 4 * i);
    __syncthreads();
    int d = tid >> 2, tq = (tid & 3) * 16;
    float vv[16];
#pragma unroll
    for (int i = 0; i < 16; i++) vv[i] = vt[tq + i][d];
#pragma unroll
    for (int i = 0; i < 16; i++) { hh[i] = f2bf(vv[i]); if (LO) lo[i] = f2bf(vv[i] - bf2f(hh[i])); }
    size_t vo = ((size_t)(bh * DH + d)) * LL + tok0 + tq;
    *(uint4*)(gb16 + VTH16 + vo)     = ((const uint4*)hh)[0];
    *(uint4*)(gb16 + VTH16 + vo + 8) = ((const uint4*)hh)[1];
    if (LO) {
        *(uint4*)(gb16 + VTL16 + vo)     = ((const uint4*)lo)[0];
        *(uint4*)(gb16 + VTL16 + vo + 8) = ((const uint4*)lo)[1];
    }
}

// ---------------- MFMA flash attention v8: swapped-operand (slot-per-lane softmax) ----------------
template<bool S3>
__global__ __launch_bounds__(256, 4) void attn_flash(int q_off, int kh_off, int kl_off,
        int vth_off, int vtl_off, int list_off, int po_off, int pml_off, int u) {
    int bid = blockIdx.x;
    int grp = bid & 127;
    int sxt = bid >> 7;                 // slot tile 0..6
    int bh = grp & 15, chunk = grp >> 4;
    int b = bh >> 3, h = bh & 7;
    int tid = threadIdx.x, lane = tid & 63, w = tid >> 6;
    int quad = lane >> 4, l15 = lane & 15;
    const int* list = (const int*)(g_buf + list_off);

    short8 qh[2], ql[2];
    {
        int slot_q = sxt * 64 + w * 16 + l15;
        int qidx = list[bh * 416 + (slot_q < u ? slot_q : u - 1)];
        const float* qp = g_buf + q_off + ((size_t)b * LL + qidx) * DM + h * DH;
#pragma unroll
        for (int d2 = 0; d2 < 2; d2++) {
            float v[8] __attribute__((aligned(16)));
            *(float4*)(v)     = *(const float4*)(qp + d2 * 32 + quad * 8);
            *(float4*)(v + 4) = *(const float4*)(qp + d2 * 32 + quad * 8 + 4);
            u16 hh[8] __attribute__((aligned(16)));
            u16 lo[8] __attribute__((aligned(16)));
#pragma unroll
            for (int j = 0; j < 8; j++) {
                float s = v[j] * 0.125f;
                u16 hi = f2bf(s); hh[j] = hi; lo[j] = f2bf(s - bf2f(hi));
            }
            qh[d2] = *(const short8*)hh; ql[d2] = *(const short8*)lo;
        }
    }

    __shared__ u16 Ksh[32 * 68];
    __shared__ u16 Ksl[S3 ? 32 * 68 : 8];
    __shared__ u16 Vth[64 * 36];
    __shared__ u16 Vtl[S3 ? 64 * 36 : 8];

    const u16* gb16 = (const u16*)g_buf;
    const u16* KHp = gb16 + kh_off + (size_t)bh * LL * DH;
    const u16* KLp = gb16 + kl_off + (size_t)bh * LL * DH;
    const u16* VHp = gb16 + vth_off + (size_t)bh * DH * LL;
    const u16* VLp = gb16 + vtl_off + (size_t)bh * DH * LL;
    int krow = tid >> 3, kcol = (tid & 7) * 8;   // K tile [32][64]
    int vd = tid >> 2, vcol = (tid & 3) * 8;     // V tile [64][32]

    int aA = ((((lane >> 4) & 1) << 5) | l15) << 2;
    int aB = aA + 64;
    bool hiT = (quad >= 2);

    uint4 pre[S3 ? 4 : 2];
    auto issue = [&](int row0) {
        pre[0] = *(const uint4*)(KHp + (size_t)(row0 + krow) * DH + kcol);
        pre[1] = *(const uint4*)(VHp + (size_t)vd * LL + row0 + vcol);
        if constexpr (S3) {
            pre[2] = *(const uint4*)(KLp + (size_t)(row0 + krow) * DH + kcol);
            pre[3] = *(const uint4*)(VLp + (size_t)vd * LL + row0 + vcol);
        }
    };
    auto commit = [&]() {
        *(uint4*)(&Ksh[krow * 68 + kcol]) = pre[0];
        *(uint4*)(&Vth[vd * 36 + vcol]) = pre[1];
        if constexpr (S3) {
            *(uint4*)(&Ksl[krow * 68 + kcol]) = pre[2];
            *(uint4*)(&Vtl[vd * 36 + vcol]) = pre[3];
        }
    };

    float m_run = -3.0e38f, l_run = 0.f;
    floatx4 acc_o[4];
#pragma unroll
    for (int j = 0; j < 4; j++) acc_o[j] = (floatx4){0.f, 0.f, 0.f, 0.f};

    issue(chunk * 256);
    for (int kt = 0; kt < 8; ++kt) {
        __syncthreads();
        commit();
        if (kt < 7) issue(chunk * 256 + (kt + 1) * 32);
        __syncthreads();
        floatx4 sacc[2];
#pragma unroll
        for (int t = 0; t < 2; t++) {
            sacc[t] = (floatx4){0.f, 0.f, 0.f, 0.f};
#pragma unroll
            for (int d2 = 0; d2 < 2; d2++) {
                int ro = (t * 16 + l15) * 68 + d2 * 32 + quad * 8;
                short8 kh = *(const short8*)(&Ksh[ro]);
                sacc[t] = __builtin_amdgcn_mfma_f32_16x16x32_bf16(kh, qh[d2], sacc[t], 0, 0, 0);
                sacc[t] = __builtin_amdgcn_mfma_f32_16x16x32_bf16(kh, ql[d2], sacc[t], 0, 0, 0);
                if constexpr (S3) {
                    short8 kl = *(const short8*)(&Ksl[ro]);
                    sacc[t] = __builtin_amdgcn_mfma_f32_16x16x32_bf16(kl, qh[d2], sacc[t], 0, 0, 0);
                }
            }
        }
        float mx = fmaxf(fmaxf(fmaxf(sacc[0][0], sacc[0][1]), fmaxf(sacc[0][2], sacc[0][3])),
                         fmaxf(fmaxf(sacc[1][0], sacc[1][1]), fmaxf(sacc[1][2], sacc[1][3])));
        mx = fmaxf(mx, __shfl_xor(mx, 16));
        mx = fmaxf(mx, __shfl_xor(mx, 32));
        float mn = fmaxf(m_run, mx);
        float alpha = __expf(m_run - mn);
        m_run = mn;
#pragma unroll
        for (int t = 0; t < 2; t++)
#pragma unroll
            for (int r = 0; r < 4; r++) sacc[t][r] = __expf(sacc[t][r] - mn);
        float ls = (sacc[0][0] + sacc[0][1]) + (sacc[0][2] + sacc[0][3])
                 + (sacc[1][0] + sacc[1][1]) + (sacc[1][2] + sacc[1][3]);
        ls += __shfl_xor(ls, 16);
        ls += __shfl_xor(ls, 32);
        l_run = l_run * alpha + ls;
        unsigned phw[2][2], plw[2][2];
#pragma unroll
        for (int t = 0; t < 2; t++)
#pragma unroll
            for (int hh = 0; hh < 2; hh++) {
                float s0 = sacc[t][2 * hh], s1 = sacc[t][2 * hh + 1];
                unsigned hw = cvtpk_bf16(s0, s1);
                phw[t][hh] = hw;
                float r0 = s0 - __uint_as_float(hw << 16);
                float r1 = s1 - __uint_as_float(hw & 0xFFFF0000u);
                plw[t][hh] = cvtpk_bf16(r0, r1);
            }
        union { unsigned wd[4]; short8 v; } pbh, pbl;
#pragma unroll
        for (int hh = 0; hh < 2; hh++) {
            int a0 = __builtin_amdgcn_ds_bpermute(aA, (int)phw[0][hh]);
            int a1 = __builtin_amdgcn_ds_bpermute(aA, (int)phw[1][hh]);
            pbh.wd[hh] = (unsigned)(hiT ? a1 : a0);
            int b0 = __builtin_amdgcn_ds_bpermute(aB, (int)phw[0][hh]);
            int b1 = __builtin_amdgcn_ds_bpermute(aB, (int)phw[1][hh]);
            pbh.wd[2 + hh] = (unsigned)(hiT ? b1 : b0);
            int c0 = __builtin_amdgcn_ds_bpermute(aA, (int)plw[0][hh]);
            int c1 = __builtin_amdgcn_ds_bpermute(aA, (int)plw[1][hh]);
            pbl.wd[hh] = (unsigned)(hiT ? c1 : c0);
            int d0 = __builtin_amdgcn_ds_bpermute(aB, (int)plw[0][hh]);
            int d1 = __builtin_amdgcn_ds_bpermute(aB, (int)plw[1][hh]);
            pbl.wd[2 + hh] = (unsigned)(hiT ? d1 : d0);
        }
#pragma unroll
        for (int j = 0; j < 4; j++)
#pragma unroll
            for (int r = 0; r < 4; r++) acc_o[j][r] *= alpha;
#pragma unroll
        for (int j = 0; j < 4; j++) {
            int ro = (j * 16 + l15) * 36 + quad * 8;
            short8 vh = *(const short8*)(&Vth[ro]);
            acc_o[j] = __builtin_amdgcn_mfma_f32_16x16x32_bf16(vh, pbh.v, acc_o[j], 0, 0, 0);
            acc_o[j] = __builtin_amdgcn_mfma_f32_16x16x32_bf16(vh, pbl.v, acc_o[j], 0, 0, 0);
            if constexpr (S3) {
                short8 vl = *(const short8*)(&Vtl[ro]);
                acc_o[j] = __builtin_amdgcn_mfma_f32_16x16x32_bf16(vl, pbh.v, acc_o[j], 0, 0, 0);
            }
        }
    }
    int slot = sxt * 64 + w * 16 + l15;
    if (slot < u) {
        size_t rec = ((size_t)(bh * NCHUNK + chunk)) * 512 + slot;
        float* po = g_buf + po_off + rec * 64;
#pragma unroll
        for (int j = 0; j < 4; j++)
            *(float4*)(po + j * 16 + quad * 4) = *(const float4*)&acc_o[j];
        if (quad == 0) {
            float* pml = g_buf + pml_off + rec * 2;
            pml[0] = m_run; pml[1] = l_run;
        }
    }
}

// ---------------- combine partials + zero unselected (rank-driven) ----------------
__global__ void attn_combine(int po_off, int pml_off, int rank_off, int u) {
    int bh = blockIdx.y;
    int b = bh >> 3, h = bh & 7;
    int tid = threadIdx.x;
    int qi = tid >> 4;
    int kb = tid & 15;
    int ds = kb * 4;
    int row = blockIdx.x * 16 + qi;
    int rank = ((const int*)(g_buf + rank_off))[bh * LL + row];
    size_t idx = ((size_t)b * LL + row) * DM + h * DH + ds;
    if (rank < 0) {
        ushort4 z = {0, 0, 0, 0};
        *(ushort4*)(((u16*)g_buf) + CTX_H + idx) = z;
        *(ushort4*)(((u16*)g_buf) + CTX_L + idx) = z;
        return;
    }
    float m = -3.0e38f;
#pragma unroll
    for (int c = 0; c < NCHUNK; c++)
        m = fmaxf(m, g_buf[pml_off + (((size_t)(bh * NCHUNK + c)) * 512 + rank) * 2]);
    float l = 0.f, O0 = 0.f, O1 = 0.f, O2 = 0.f, O3 = 0.f;
#pragma unroll
    for (int c = 0; c < NCHUNK; c++) {
        size_t rec = ((size_t)(bh * NCHUNK + c)) * 512 + rank;
        const float* pml = g_buf + pml_off + rec * 2;
        float a = __expf(pml[0] - m);
        l += a * pml[1];
        float4 o = *(const float4*)(g_buf + po_off + rec * 64 + ds);
        O0 += a * o.x; O1 += a * o.y; O2 += a * o.z; O3 += a * o.w;
    }
    float inv = 1.0f / l;
    float o0 = O0 * inv, o1 = O1 * inv, o2 = O2 * inv, o3 = O3 * inv;
    ushort4 hv, lv;
    hv.x = f2bf(o0); lv.x = f2bf(o0 - bf2f(hv.x));
    hv.y = f2bf(o1); lv.y = f2bf(o1 - bf2f(hv.y));
    hv.z = f2bf(o2); lv.z = f2bf(o2 - bf2f(hv.z));
    hv.w = f2bf(o3); lv.w = f2bf(o3 - bf2f(hv.w));
    *(ushort4*)(((u16*)g_buf) + CTX_H + idx) = hv;
    *(ushort4*)(((u16*)g_buf) + CTX_L + idx) = lv;
}

// ---------------- orchestration: 23 launches ----------------
extern "C" void kernel_launch(void* const* d_in, const int* in_sizes, int n_in,
                              void* d_out, int out_size, void* d_ws, size_t ws_size,
                              hipStream_t stream) {
    static const int SZ[28] = {
        2097152, 2097152,
        262144, 512, 262144, 512, 262144, 512, 262144, 512,
        262144, 512, 262144, 512, 262144, 512, 262144, 512,
        1048576, 2048, 1048576, 512,
        512, 512, 512, 512, 512, 512
    };
    int OFF[28];
    int cur = 0;
    for (int i = 0; i < 28; i++) { OFF[i] = cur; cur += SZ[i]; }

    P28 ps;
    for (int i = 0; i < 28; i++) ps.p[i] = d_in[i];
    prep_all<<<3072, 256, 0, stream>>>(ps);

    auto select_attend = [&](bool sa) {
        if (sa) kvprep_k<true><<<dim3(32, 16), 256, 0, stream>>>(A_K, A_V);
        else    kvprep_k<false><<<dim3(32, 16), 256, 0, stream>>>(A_K, A_V);
        meankn_p1<<<16 * 32, 256, 0, stream>>>(A_K, A_PARTK);
        mscore_k<<<dim3(64, 16), 256, 0, stream>>>(A_Q, A_PARTK, A_MS);
        topsel_k<<<dim3(32, 16), 256, 0, stream>>>(A_MS, A_LIST, A_RANK, UU);
        if (sa)
            attn_flash<true><<<896, 256, 0, stream>>>(
                A_Q, KH16, KL16, VTH16, VTL16, A_LIST, A_PO, A_PML, UU);
        else
            attn_flash<false><<<896, 256, 0, stream>>>(
                A_Q, KH16, KL16, VTH16, VTL16, A_LIST, A_PO, A_PML, UU);
        attn_combine<<<dim3(128, 16), 256, 0, stream>>>(A_PO, A_PML, A_RANK, UU);
    };

    // ---- LN1 + self-attention (QKV fused N=1536, sectioned -> A_Q/A_K/A_V) ----
    lnorm_k<<<ROWS, 256, 0, stream>>>(OFF[0], OFF[22], OFF[23], XN_H, XN_L);
    mgemm_k<2, true, true, false, false, false, false><<<dim3(64, 12), 256, 0, stream>>>(
        I3{{XN_H, XN_H, XN_H}}, I3{{1, 1, 1}}, I3{{0, 0, 0}},
        WT_SAQKV, I3{{OFF[3], OFF[5], OFF[7]}}, 0, A_Q, nullptr, ROWS, 1536, 512);
    select_attend(true);
    sgemm_k<true, true, false><<<2048, 64, 0, stream>>>(
        CTX_H, 1, 0, WT_SAO, OFF[9], OFF[0], OFF[0], nullptr, ROWS, 512, 512);

    // ---- LN2 + cross-attention (caQ; caK+caV fused N=1024 on combined WT_CAKV slot) ----
    lnorm_k<<<ROWS, 256, 0, stream>>>(OFF[0], OFF[24], OFF[25], XN_H, XN_L);
    sgemm_k<true, false, false><<<2048, 64, 0, stream>>>(
        XN_H, 1, 0, WT_CAQ, OFF[11], 0, A_Q, nullptr, ROWS, 512, 512);
    mgemm_k<2, true, true, false, false, false, false><<<dim3(64, 8), 256, 0, stream>>>(
        I3{{ENC_H, ENC_H, ENC_H}}, I3{{1, 0, 0}}, I3{{1, 0, 0}},
        WT_CAKV, I3{{OFF[13], OFF[15], 0}}, 0, A_K, nullptr, ROWS, 1024, 512);
    select_attend(false);
    sgemm_k<false, true, false><<<2048, 64, 0, stream>>>(
        CTX_H, 0, 0, WT_CAO, OFF[17], OFF[0], OFF[0], nullptr, ROWS, 512, 512);

    // ---- LN3 + FFN ----
    lnorm_k<<<ROWS, 256, 0, stream>>>(OFF[0], OFF[26], OFF[27], XN_H, XN_L);
    mgemm_k<4, false, false, true, false, false, true><<<dim3(32, 16), 256, 0, stream>>>(
        I3{{XN_H, 0, 0}}, I3{{0, 0, 0}}, I3{{0, 0, 0}},
        WT_W1, I3{{OFF[19], 0, 0}}, 0, AH_H, nullptr, ROWS, 2048, 512);
    sgemm_k<false, true, true><<<2048, 64, 0, stream>>>(
        AH_H, 0, 0, WT_W2, OFF[21], OFF[0], 0, d_out, ROWS, 512, 2048);
}

// Round 8
// 543.244 us; speedup vs baseline: 1.2314x; 1.2314x over previous
//
#include <hip/hip_runtime.h>

// ---------------- constants ----------------
#define BB 2
#define LL 2048
#define DM 512
#define NH 8
#define DH 64
#define DFF 2048
#define UU 409          // max(1, 2048/5)
#define ROWS (BB*LL)    // 4096
#define X_ELEMS 2097152
#define NCHUNK 8        // K-split chunks (256 keys each) in flash attention

typedef unsigned short u16;
typedef __attribute__((ext_vector_type(8))) short short8;
typedef __attribute__((ext_vector_type(4))) float floatx4;

// ---- static scratch arena (~153 MB). No d_ws dependence. ----
#define G_TOTAL 38200000
__device__ float g_buf[G_TOTAL];
__device__ int   g_isbf16;

// arena layout (float offsets)
#define A_Q     10495488  // fp32 (A_K, A_V consecutive — SEC writes rely on this)
#define A_K     12592640
#define A_V     14689792
#define A_MKN   25175552
#define A_MS    25176576
#define A_RANK  25209344  // [16][2048] int
#define A_PARTK 25242112
#define A_LIST  25274880
#define A_PO    25281536  // [16 bh][8 chunk][512 slot][64] fp32
#define A_PML   29475840  // [16][8][512][2] fp32 -> end 29606912
#define A_CTXF  16786944
// u16 offsets
#define XN_H    16796672
#define XN_L    18893824
#define CTX_H   33573888
#define CTX_L   35671040
#define ENC_H   37768192
#define ENC_L   39865344
#define AH_H    41962496
// pre-converted K/V for attention (bf16 hi/lo, V transposed per bh):
#define KH16    59213824  // [bh][2048][64]
#define KL16    61310976
#define VTH16   63408128  // [bh][64][2048]
#define VTL16   65505280
#define WT_SAQKV 67864576   // N=1536 K=512: hi 786432, lo +786432
#define WT_SAO   69437440   // N=512: hi 262144, lo +262144
#define WT_CAQKV 69961728   // fused caQ+caK+caV: N=1536 K=512, hi 786432, lo +786432
#define WT_CAO   71534592
#define WT_W1    72058880   // N=2048 K=512
#define WT_W2    74156032   // N=512 K=2048
// end u16 = 76,253,184 = 38,126,592 floats < G_TOTAL ✓

__constant__ int c_end[28] = {
    2097152, 4194304, 4456448, 4456960, 4719104, 4719616, 4981760, 4982272,
    5244416, 5244928, 5507072, 5507584, 5769728, 5770240, 6032384, 6032896,
    6295040, 6295552, 7344128, 7346176, 8394752, 8395264, 8395776, 8396288,
    8396800, 8397312, 8397824, 8398336
};
__constant__ int sm_idx[16] = {3,5,7,9,11,13,15,17,19,21,22,23,24,25,26,27};
__constant__ int sm_cum[16] = {64,128,192,256,320,384,448,512,768,832,896,960,1024,1088,1152,1216};
#define XG 262144
#define EG 262144
#define SG 1216

__device__ __forceinline__ float bf2f(u16 x) {
    union { unsigned int u; float f; } c; c.u = ((unsigned int)x) << 16; return c.f;
}
__device__ __forceinline__ u16 f2bf(float f) {
    union { float f; unsigned int u; } c; c.f = f;
    unsigned int u = c.u;
    return (u16)((u + 0x7FFFu + ((u >> 16) & 1u)) >> 16);
}
// pack two f32 -> bf16 pair (low = a, high = b), RNE
__device__ __forceinline__ unsigned cvtpk_bf16(float a, float b) {
    unsigned r;
    asm("v_cvt_pk_bf16_f32 %0, %1, %2" : "=v"(r) : "v"(a), "v"(b));
    return r;
}

struct P28 { const void* p[28]; };
struct I3 { int v[3]; };

// ---------------- prep_all: weight transpose (blocks 0..1023) + canonicalize (1024..3071) ----------------
__constant__ int tj[10][6] = {
    {2,  WT_SAQKV, 0,    512,  786432, 8},   // sa_wq
    {4,  WT_SAQKV, 512,  512,  786432, 8},   // sa_wk
    {6,  WT_SAQKV, 1024, 512,  786432, 8},   // sa_wv
    {8,  WT_SAO,   0,    512,  262144, 8},   // sa_wo
    {10, WT_CAQKV, 0,    512,  786432, 8},   // ca_wq  (fused N=1536 slot)
    {12, WT_CAQKV, 512,  512,  786432, 8},   // ca_wk
    {14, WT_CAQKV, 1024, 512,  786432, 8},   // ca_wv
    {16, WT_CAO,   0,    512,  262144, 8},   // ca_wo
    {18, WT_W1,    0,    512, 1048576, 32},  // ff_w1
    {20, WT_W2,    0,   2048, 1048576, 8},   // ff_w2
};
__constant__ int tcum[10] = {64, 128, 192, 256, 320, 384, 448, 512, 768, 1024};
__global__ void prep_all(P28 ps) {
    const int f = (((const u16*)ps.p[22])[0] == 0x3F80u) ? 1 : 0;
    if (blockIdx.x == 0 && threadIdx.x == 0) g_isbf16 = f;
    u16* gb16 = (u16*)g_buf;
    if (blockIdx.x < 1024) {
        int bid = blockIdx.x;
        int j = 0;
        while (bid >= tcum[j]) j++;
        int t = bid - (j ? tcum[j - 1] : 0);
        int widx = tj[j][0], wt = tj[j][1], col0 = tj[j][2];
        int K = tj[j][3], lo = tj[j][4], txn = tj[j][5];
        int Nsrc = txn * 64;
        int n0 = (t % txn) * 64, k0 = (t / txn) * 64;
        __shared__ float tb[64][65];
        int c = threadIdx.x & 63, r0 = threadIdx.x >> 6;
        const void* W = ps.p[widx];
        u16* WTh = gb16 + wt;
        for (int i = 0; i < 16; i++) {
            int r = r0 + 4 * i;
            size_t src = (size_t)(k0 + r) * Nsrc + n0 + c;
            tb[r][c] = f ? bf2f(((const u16*)W)[src]) : ((const float*)W)[src];
        }
        __syncthreads();
        for (int i = 0; i < 16; i++) {
            int r = r0 + 4 * i;
            float v = tb[c][r];
            u16 hi = f2bf(v);
            size_t o = (size_t)(col0 + n0 + r) * K + k0 + c;
            WTh[o] = hi;
            WTh[lo + o] = f2bf(v - bf2f(hi));
        }
        return;
    }
    int stride = 2048 * blockDim.x;
    for (int g = (blockIdx.x - 1024) * blockDim.x + threadIdx.x; g < XG + EG + SG; g += stride) {
        if (g < XG) {
            int e = g * 8;
            if (f) {
                uint4 raw = ((const uint4*)ps.p[0])[g];
                const u16* rr = (const u16*)&raw;
                float v[8] __attribute__((aligned(16)));
#pragma unroll
                for (int i = 0; i < 8; i++) v[i] = bf2f(rr[i]);
                *(float4*)(g_buf + e) = ((const float4*)v)[0];
                *(float4*)(g_buf + e + 4) = ((const float4*)v)[1];
            } else {
                *(uint4*)(g_buf + e)     = ((const uint4*)ps.p[0])[g * 2];
                *(uint4*)(g_buf + e + 4) = ((const uint4*)ps.p[0])[g * 2 + 1];
            }
        } else if (g < XG + EG) {
            int gl = g - XG;
            int e = gl * 8;
            float v[8] __attribute__((aligned(16)));
            if (f) {
                uint4 raw = ((const uint4*)ps.p[1])[gl];
                const u16* rr = (const u16*)&raw;
#pragma unroll
                for (int i = 0; i < 8; i++) v[i] = bf2f(rr[i]);
            } else {
                *(float4*)(v)     = ((const float4*)ps.p[1])[gl * 2];
                *(float4*)(v + 4) = ((const float4*)ps.p[1])[gl * 2 + 1];
            }
            u16 hh[8] __attribute__((aligned(16)));
            u16 lo[8] __attribute__((aligned(16)));
#pragma unroll
            for (int i = 0; i < 8; i++) { u16 hi = f2bf(v[i]); hh[i] = hi; lo[i] = f2bf(v[i] - bf2f(hi)); }
            *(uint4*)(&gb16[ENC_H + e]) = *(const uint4*)hh;
            *(uint4*)(&gb16[ENC_L + e]) = *(const uint4*)lo;
        } else {
            int t = g - XG - EG;
            int si = 0;
            while (t >= sm_cum[si]) si++;
            int s = sm_idx[si];
            int gl = t - (si ? sm_cum[si - 1] : 0);
            int e = gl * 8;
            float* dst = g_buf + c_end[s - 1] + e;
            if (f) {
                uint4 raw = *(const uint4*)((const u16*)ps.p[s] + e);
                const u16* rr = (const u16*)&raw;
#pragma unroll
                for (int i = 0; i < 8; i++) dst[i] = bf2f(rr[i]);
            } else {
                *(uint4*)(dst)     = *(const uint4*)((const float*)ps.p[s] + e);
                *(uint4*)(dst + 4) = *(const uint4*)((const float*)ps.p[s] + e + 4);
            }
        }
    }
}

// ---------------- layernorm: fp32 in, bf16 hi/lo out ----------------
__global__ void lnorm_k(int x_off, int g_off, int b_off, int yh_u16, int yl_u16) {
    int row = blockIdx.x;
    int tid = threadIdx.x;
    const float* x = g_buf + x_off + (size_t)row * DM;
    float a = x[tid], c = x[tid + 256];
    float s1 = a + c, s2 = a * a + c * c;
    for (int o = 32; o > 0; o >>= 1) { s1 += __shfl_xor(s1, o); s2 += __shfl_xor(s2, o); }
    __shared__ float r1[4], r2[4];
    int wave = tid >> 6, lane = tid & 63;
    if (lane == 0) { r1[wave] = s1; r2[wave] = s2; }
    __syncthreads();
    s1 = r1[0] + r1[1] + r1[2] + r1[3];
    s2 = r2[0] + r2[1] + r2[2] + r2[3];
    float mean = s1 * (1.0f / DM);
    float var  = s2 * (1.0f / DM) - mean * mean;
    float rstd = rsqrtf(var + 1e-5f);
    const float* gg = g_buf + g_off;
    const float* bb = g_buf + b_off;
    u16* yh = ((u16*)g_buf) + yh_u16 + (size_t)row * DM;
    u16* yl = ((u16*)g_buf) + yl_u16 + (size_t)row * DM;
    float v1 = (a - mean) * rstd * gg[tid]       + bb[tid];
    float v2 = (c - mean) * rstd * gg[tid + 256] + bb[tid + 256];
    u16 h1 = f2bf(v1), h2 = f2bf(v2);
    yh[tid] = h1;       yl[tid] = f2bf(v1 - bf2f(h1));
    yh[tid + 256] = h2; yl[tid + 256] = f2bf(v2 - bf2f(h2));
}

// ---------------- MFMA bf16 GEMM (XCD = mt%8: blockIdx.x = m-tile, blockIdx.y = n-tile) ----------------
// Round-7 T14 staging reverted (regressed ~16µs/dispatch: extra VGPR pressure, same barriers).
template<int WM, bool SPLIT, bool SEC, bool RELU, bool RESID, bool FINAL, bool OUTH>
__global__ void mgemm_k(I3 a_offs, I3 splt, I3 alz, int wt_u16_off, I3 boffs, int resid_off,
                        int out_off, void* __restrict__ dext, int M, int N, int K) {
    constexpr int BT_M = WM * 32;
    constexpr int A4 = BT_M * 4;
    __shared__ u16 Ash[BT_M * 40];
    __shared__ u16 Asl[SPLIT ? BT_M * 40 : 8];
    __shared__ u16 Bsh[128 * 40];
    __shared__ u16 Bsl[SPLIT ? 128 * 40 : 8];
    int ntb = blockIdx.y;
    int sec_blk = SEC ? ((ntb * 128) >> 9) : 0;
    const u16* Ah = ((const u16*)g_buf) + a_offs.v[sec_blk];
    const u16* Al = Ah + (size_t)M * K;
    const u16* WTh = ((const u16*)g_buf) + wt_u16_off;
    const u16* WTl = WTh + (size_t)N * K;
    const int isbf = g_isbf16;
    const bool use_al = SPLIT && splt.v[sec_blk] && !(alz.v[sec_blk] && isbf);
    const bool use_bl = SPLIT && splt.v[sec_blk] && !isbf;
    int tid = threadIdx.x;
    int lane = tid & 63, wid = tid >> 6;
    int wm = wid >> 1, wn = wid & 1;
    int quad = lane >> 4, l15 = lane & 15;
    int m0 = blockIdx.x * BT_M, n0 = ntb * 128;
    floatx4 acc[WM][4];
#pragma unroll
    for (int i = 0; i < WM; i++)
#pragma unroll
        for (int j = 0; j < 4; j++) acc[i][j] = (floatx4){0.f, 0.f, 0.f, 0.f};
    for (int k0 = 0; k0 < K; k0 += 32) {
#pragma unroll
        for (int i = 0; i < (A4 + 255) / 256; i++) {
            int idx8 = tid + 256 * i;
            if (A4 % 256 == 0 || idx8 < A4) {
                int r = idx8 >> 2, c8 = (idx8 & 3) * 8;
                *(uint4*)(&Ash[r * 40 + c8]) = *(const uint4*)(Ah + (size_t)(m0 + r) * K + k0 + c8);
                if (SPLIT && use_al)
                    *(uint4*)(&Asl[r * 40 + c8]) = *(const uint4*)(Al + (size_t)(m0 + r) * K + k0 + c8);
            }
        }
#pragma unroll
        for (int i = 0; i < 2; i++) {
            int idx8 = tid + 256 * i;
            int r = idx8 >> 2, c8 = (idx8 & 3) * 8;
            *(uint4*)(&Bsh[r * 40 + c8]) = *(const uint4*)(WTh + (size_t)(n0 + r) * K + k0 + c8);
            if (SPLIT && use_bl)
                *(uint4*)(&Bsl[r * 40 + c8]) = *(const uint4*)(WTl + (size_t)(n0 + r) * K + k0 + c8);
        }
        __syncthreads();
        short8 ah[WM], bh[4], al[WM], bl[4];
#pragma unroll
        for (int i = 0; i < WM; i++) {
            int ro = (wm * WM * 16 + i * 16 + l15) * 40 + quad * 8;
            ah[i] = *(const short8*)(&Ash[ro]);
            if (SPLIT && use_al) al[i] = *(const short8*)(&Asl[ro]);
        }
#pragma unroll
        for (int j = 0; j < 4; j++) {
            int ro = (wn * 64 + j * 16 + l15) * 40 + quad * 8;
            bh[j] = *(const short8*)(&Bsh[ro]);
            if (SPLIT && use_bl) bl[j] = *(const short8*)(&Bsl[ro]);
        }
#pragma unroll
        for (int i = 0; i < WM; i++)
#pragma unroll
            for (int j = 0; j < 4; j++) {
                acc[i][j] = __builtin_amdgcn_mfma_f32_16x16x32_bf16(ah[i], bh[j], acc[i][j], 0, 0, 0);
                if constexpr (SPLIT) {
                    if (use_bl)
                        acc[i][j] = __builtin_amdgcn_mfma_f32_16x16x32_bf16(ah[i], bl[j], acc[i][j], 0, 0, 0);
                    if (use_al)
                        acc[i][j] = __builtin_amdgcn_mfma_f32_16x16x32_bf16(al[i], bh[j], acc[i][j], 0, 0, 0);
                }
            }
        __syncthreads();
    }
#pragma unroll
    for (int i = 0; i < WM; i++)
#pragma unroll
        for (int j = 0; j < 4; j++)
#pragma unroll
            for (int r = 0; r < 4; r++) {
                int row = m0 + wm * WM * 16 + i * 16 + quad * 4 + r;
                int col = n0 + wn * 64 + j * 16 + l15;
                int sec = SEC ? (col >> 9) : 0;
                int ci  = SEC ? (col & 511) : col;
                float v = acc[i][j][r] + g_buf[boffs.v[sec] + ci];
                if (RELU) v = fmaxf(v, 0.f);
                if (RESID) v += g_buf[resid_off + (size_t)row * N + col];
                if (FINAL) {
                    if (g_isbf16) ((u16*)dext)[(size_t)row * N + col] = f2bf(v);
                    else          ((float*)dext)[(size_t)row * N + col] = v;
                } else if (OUTH) {
                    ((u16*)g_buf)[out_off + (size_t)row * N + col] = f2bf(v);
                } else if (SEC) {
                    g_buf[out_off + ((size_t)sec * ROWS + row) * 512 + ci] = v;
                } else {
                    g_buf[out_off + (size_t)row * N + col] = v;
                }
            }
}

// ---------------- mean score (fused p2): grid (64 chunks, 16 bh), 32 rows/block ----------------
__global__ void mscore_k(int q_off, int part_off, int ms_off) {
    int bh = blockIdx.y, b = bh >> 3, h = bh & 7;
    int tid = threadIdx.x;
    __shared__ float mk[64];
    if (tid < 64) {
        float s = 0.f;
        for (int c = 0; c < 32; c++) s += g_buf[part_off + (size_t)(bh * 32 + c) * 64 + tid];
        mk[tid] = s * (1.0f / LL);
    }
    __syncthreads();
    int w = tid >> 6, lane = tid & 63;
    float m = mk[lane];
#pragma unroll
    for (int it = 0; it < 8; it++) {
        int row = blockIdx.x * 32 + it * 4 + w;
        float qv = g_buf[q_off + ((size_t)b * LL + row) * DM + h * DH + lane];
        float s = qv * qv, d = qv * m;
        for (int o = 32; o > 0; o >>= 1) { s += __shfl_xor(s, o); d += __shfl_xor(d, o); }
        if (lane == 0) g_buf[ms_off + bh * LL + row] = d / sqrtf(fmaxf(s, 1e-30f));
    }
}

// ---------------- top-u: rank-count -> score-ordered list + rank map ----------------
__global__ void topsel_k(int ms_off, int list_off, int rank_off, int u) {
    __shared__ float s[LL];
    int bh = blockIdx.y, chunk = blockIdx.x;
    for (int i = threadIdx.x; i < LL; i += 256) s[i] = g_buf[ms_off + bh * LL + i];
    __syncthreads();
    int il = threadIdx.x >> 2;
    int i = chunk * 64 + il;
    int jq = threadIdx.x & 3;
    float si = s[i];
    int cnt = 0;
    for (int t = 0; t < 512; t++) {
        int j = jq * 512 + t;
        float sj = s[j];
        cnt += (sj > si) || (sj == si && j < i);
    }
    cnt += __shfl_xor(cnt, 1);
    cnt += __shfl_xor(cnt, 2);
    if (jq == 0) {
        int* list = (int*)(g_buf + list_off);
        int* rank = (int*)(g_buf + rank_off);
        if (cnt < u) { list[bh * 416 + cnt] = i; rank[bh * LL + i] = cnt; }
        else rank[bh * LL + i] = -1;
    }
}

// ---------------- kvprep + fused meankn: fp32 K/V -> bf16 hi/lo, V^T, K-norm partials ----------------
// grid (32 tok-tiles, 16 bh). Fuses meankn_p1: per tok-tile, column sums of L2-normalized
// K rows -> A_PARTK[(bh*32+tile)*64 + d] (same layout mscore_k reads).
template<bool LO>
__global__ void kvprep_k(int k_off, int v_off, int part_off) {
    int bh = blockIdx.y, b = bh >> 3, h = bh & 7;
    int tok0 = blockIdx.x * 64;
    int tid = threadIdx.x;
    __shared__ float vt[64][68];
    u16* gb16 = (u16*)g_buf;
    int tok = tid >> 2, dq = (tid & 3) * 16;
    const float* kp = g_buf + k_off + ((size_t)(b * LL + tok0 + tok)) * DM + h * DH + dq;
    const float* vp = g_buf + v_off + ((size_t)(b * LL + tok0 + tok)) * DM + h * DH + dq;
    float kv[16] __attribute__((aligned(16)));
#pragma unroll
    for (int i = 0; i < 4; i++) *(float4*)(kv + 4 * i) = *(const float4*)(kp + 4 * i);
    u16 hh[16] __attribute__((aligned(16)));
    u16 lo[16] __attribute__((aligned(16)));
#pragma unroll
    for (int i = 0; i < 16; i++) { hh[i] = f2bf(kv[i]); if (LO) lo[i] = f2bf(kv[i] - bf2f(hh[i])); }
    size_t ko = ((size_t)(bh * LL + tok0 + tok)) * DH + dq;
    *(uint4*)(gb16 + KH16 + ko)     = ((const uint4*)hh)[0];
    *(uint4*)(gb16 + KH16 + ko + 8) = ((const uint4*)hh)[1];
    if (LO) {
        *(uint4*)(gb16 + KL16 + ko)     = ((const uint4*)lo)[0];
        *(uint4*)(gb16 + KL16 + ko + 8) = ((const uint4*)lo)[1];
    }
    // ---- fused meankn: normalized-K column partials ----
    {
        float s = 0.f;
#pragma unroll
        for (int i = 0; i < 16; i++) s += kv[i] * kv[i];
        s += __shfl_xor(s, 1);
        s += __shfl_xor(s, 2);
        float sq = sqrtf(fmaxf(s, 1e-30f));
#pragma unroll
        for (int i = 0; i < 16; i++) vt[tok][dq + i] = kv[i] / sq;
    }
    __syncthreads();
    if (tid < 64) {
        float acc = 0.f;
        for (int t = 0; t < 64; t++) acc += vt[t][tid];
        g_buf[part_off + ((size_t)(bh * 32 + blockIdx.x)) * 64 + tid] = acc;
    }
    __syncthreads();
    // ---- V transpose ----
#pragma unroll
    for (int i = 0; i < 4; i++) *(float4*)(&vt[tok][dq + 4 * i]) = *(const float4*)(vp + 4 * i);
    __syncthreads();
    int d = tid >> 2, tq = (tid & 3) * 16;
    float vv[16];
#pragma unroll
    for (int i = 0; i < 16; i++) vv[i] = vt[tq + i][d];
#pragma unroll
    for (int i = 0; i < 16; i++) { hh[i] = f2bf(vv[i]); if (LO) lo[i] = f2bf(vv[i] - bf2f(hh[i])); }
    size_t vo = ((size_t)(bh * DH + d)) * LL + tok0 + tq;
    *(uint4*)(gb16 + VTH16 + vo)     = ((const uint4*)hh)[0];
    *(uint4*)(gb16 + VTH16 + vo + 8) = ((const uint4*)hh)[1];
    if (LO) {
        *(uint4*)(gb16 + VTL16 + vo)     = ((const uint4*)lo)[0];
        *(uint4*)(gb16 + VTL16 + vo + 8) = ((const uint4*)lo)[1];
    }
}

// ---------------- MFMA flash attention v8: swapped-operand (slot-per-lane softmax) ----------------
template<bool S3>
__global__ __launch_bounds__(256, 4) void attn_flash(int q_off, int kh_off, int kl_off,
        int vth_off, int vtl_off, int list_off, int po_off, int pml_off, int u) {
    int bid = blockIdx.x;
    int grp = bid & 127;
    int sxt = bid >> 7;                 // slot tile 0..6
    int bh = grp & 15, chunk = grp >> 4;
    int b = bh >> 3, h = bh & 7;
    int tid = threadIdx.x, lane = tid & 63, w = tid >> 6;
    int quad = lane >> 4, l15 = lane & 15;
    const int* list = (const int*)(g_buf + list_off);

    short8 qh[2], ql[2];
    {
        int slot_q = sxt * 64 + w * 16 + l15;
        int qidx = list[bh * 416 + (slot_q < u ? slot_q : u - 1)];
        const float* qp = g_buf + q_off + ((size_t)b * LL + qidx) * DM + h * DH;
#pragma unroll
        for (int d2 = 0; d2 < 2; d2++) {
            float v[8] __attribute__((aligned(16)));
            *(float4*)(v)     = *(const float4*)(qp + d2 * 32 + quad * 8);
            *(float4*)(v + 4) = *(const float4*)(qp + d2 * 32 + quad * 8 + 4);
            u16 hh[8] __attribute__((aligned(16)));
            u16 lo[8] __attribute__((aligned(16)));
#pragma unroll
            for (int j = 0; j < 8; j++) {
                float s = v[j] * 0.125f;
                u16 hi = f2bf(s); hh[j] = hi; lo[j] = f2bf(s - bf2f(hi));
            }
            qh[d2] = *(const short8*)hh; ql[d2] = *(const short8*)lo;
        }
    }

    __shared__ u16 Ksh[32 * 68];
    __shared__ u16 Ksl[S3 ? 32 * 68 : 8];
    __shared__ u16 Vth[64 * 36];
    __shared__ u16 Vtl[S3 ? 64 * 36 : 8];

    const u16* gb16 = (const u16*)g_buf;
    const u16* KHp = gb16 + kh_off + (size_t)bh * LL * DH;
    const u16* KLp = gb16 + kl_off + (size_t)bh * LL * DH;
    const u16* VHp = gb16 + vth_off + (size_t)bh * DH * LL;
    const u16* VLp = gb16 + vtl_off + (size_t)bh * DH * LL;
    int krow = tid >> 3, kcol = (tid & 7) * 8;   // K tile [32][64]
    int vd = tid >> 2, vcol = (tid & 3) * 8;     // V tile [64][32]

    int aA = ((((lane >> 4) & 1) << 5) | l15) << 2;
    int aB = aA + 64;
    bool hiT = (quad >= 2);

    uint4 pre[S3 ? 4 : 2];
    auto issue = [&](int row0) {
        pre[0] = *(const uint4*)(KHp + (size_t)(row0 + krow) * DH + kcol);
        pre[1] = *(const uint4*)(VHp + (size_t)vd * LL + row0 + vcol);
        if constexpr (S3) {
            pre[2] = *(const uint4*)(KLp + (size_t)(row0 + krow) * DH + kcol);
            pre[3] = *(const uint4*)(VLp + (size_t)vd * LL + row0 + vcol);
        }
    };
    auto commit = [&]() {
        *(uint4*)(&Ksh[krow * 68 + kcol]) = pre[0];
        *(uint4*)(&Vth[vd * 36 + vcol]) = pre[1];
        if constexpr (S3) {
            *(uint4*)(&Ksl[krow * 68 + kcol]) = pre[2];
            *(uint4*)(&Vtl[vd * 36 + vcol]) = pre[3];
        }
    };

    float m_run = -3.0e38f, l_run = 0.f;
    floatx4 acc_o[4];
#pragma unroll
    for (int j = 0; j < 4; j++) acc_o[j] = (floatx4){0.f, 0.f, 0.f, 0.f};

    issue(chunk * 256);
    for (int kt = 0; kt < 8; ++kt) {
        __syncthreads();
        commit();
        if (kt < 7) issue(chunk * 256 + (kt + 1) * 32);
        __syncthreads();
        floatx4 sacc[2];
#pragma unroll
        for (int t = 0; t < 2; t++) {
            sacc[t] = (floatx4){0.f, 0.f, 0.f, 0.f};
#pragma unroll
            for (int d2 = 0; d2 < 2; d2++) {
                int ro = (t * 16 + l15) * 68 + d2 * 32 + quad * 8;
                short8 kh = *(const short8*)(&Ksh[ro]);
                sacc[t] = __builtin_amdgcn_mfma_f32_16x16x32_bf16(kh, qh[d2], sacc[t], 0, 0, 0);
                sacc[t] = __builtin_amdgcn_mfma_f32_16x16x32_bf16(kh, ql[d2], sacc[t], 0, 0, 0);
                if constexpr (S3) {
                    short8 kl = *(const short8*)(&Ksl[ro]);
                    sacc[t] = __builtin_amdgcn_mfma_f32_16x16x32_bf16(kl, qh[d2], sacc[t], 0, 0, 0);
                }
            }
        }
        float mx = fmaxf(fmaxf(fmaxf(sacc[0][0], sacc[0][1]), fmaxf(sacc[0][2], sacc[0][3])),
                         fmaxf(fmaxf(sacc[1][0], sacc[1][1]), fmaxf(sacc[1][2], sacc[1][3])));
        mx = fmaxf(mx, __shfl_xor(mx, 16));
        mx = fmaxf(mx, __shfl_xor(mx, 32));
        float mn = fmaxf(m_run, mx);
        float alpha = __expf(m_run - mn);
        m_run = mn;
#pragma unroll
        for (int t = 0; t < 2; t++)
#pragma unroll
            for (int r = 0; r < 4; r++) sacc[t][r] = __expf(sacc[t][r] - mn);
        float ls = (sacc[0][0] + sacc[0][1]) + (sacc[0][2] + sacc[0][3])
                 + (sacc[1][0] + sacc[1][1]) + (sacc[1][2] + sacc[1][3]);
        ls += __shfl_xor(ls, 16);
        ls += __shfl_xor(ls, 32);
        l_run = l_run * alpha + ls;
        unsigned phw[2][2], plw[2][2];
#pragma unroll
        for (int t = 0; t < 2; t++)
#pragma unroll
            for (int hh = 0; hh < 2; hh++) {
                float s0 = sacc[t][2 * hh], s1 = sacc[t][2 * hh + 1];
                unsigned hw = cvtpk_bf16(s0, s1);
                phw[t][hh] = hw;
                float r0 = s0 - __uint_as_float(hw << 16);
                float r1 = s1 - __uint_as_float(hw & 0xFFFF0000u);
                plw[t][hh] = cvtpk_bf16(r0, r1);
            }
        union { unsigned wd[4]; short8 v; } pbh, pbl;
#pragma unroll
        for (int hh = 0; hh < 2; hh++) {
            int a0 = __builtin_amdgcn_ds_bpermute(aA, (int)phw[0][hh]);
            int a1 = __builtin_amdgcn_ds_bpermute(aA, (int)phw[1][hh]);
            pbh.wd[hh] = (unsigned)(hiT ? a1 : a0);
            int b0 = __builtin_amdgcn_ds_bpermute(aB, (int)phw[0][hh]);
            int b1 = __builtin_amdgcn_ds_bpermute(aB, (int)phw[1][hh]);
            pbh.wd[2 + hh] = (unsigned)(hiT ? b1 : b0);
            int c0 = __builtin_amdgcn_ds_bpermute(aA, (int)plw[0][hh]);
            int c1 = __builtin_amdgcn_ds_bpermute(aA, (int)plw[1][hh]);
            pbl.wd[hh] = (unsigned)(hiT ? c1 : c0);
            int d0 = __builtin_amdgcn_ds_bpermute(aB, (int)plw[0][hh]);
            int d1 = __builtin_amdgcn_ds_bpermute(aB, (int)plw[1][hh]);
            pbl.wd[2 + hh] = (unsigned)(hiT ? d1 : d0);
        }
#pragma unroll
        for (int j = 0; j < 4; j++)
#pragma unroll
            for (int r = 0; r < 4; r++) acc_o[j][r] *= alpha;
#pragma unroll
        for (int j = 0; j < 4; j++) {
            int ro = (j * 16 + l15) * 36 + quad * 8;
            short8 vh = *(const short8*)(&Vth[ro]);
            acc_o[j] = __builtin_amdgcn_mfma_f32_16x16x32_bf16(vh, pbh.v, acc_o[j], 0, 0, 0);
            acc_o[j] = __builtin_amdgcn_mfma_f32_16x16x32_bf16(vh, pbl.v, acc_o[j], 0, 0, 0);
            if constexpr (S3) {
                short8 vl = *(const short8*)(&Vtl[ro]);
                acc_o[j] = __builtin_amdgcn_mfma_f32_16x16x32_bf16(vl, pbh.v, acc_o[j], 0, 0, 0);
            }
        }
    }
    int slot = sxt * 64 + w * 16 + l15;
    if (slot < u) {
        size_t rec = ((size_t)(bh * NCHUNK + chunk)) * 512 + slot;
        float* po = g_buf + po_off + rec * 64;
#pragma unroll
        for (int j = 0; j < 4; j++)
            *(float4*)(po + j * 16 + quad * 4) = *(const float4*)&acc_o[j];
        if (quad == 0) {
            float* pml = g_buf + pml_off + rec * 2;
            pml[0] = m_run; pml[1] = l_run;
        }
    }
}

// ---------------- combine partials + zero unselected (rank-driven) ----------------
__global__ void attn_combine(int po_off, int pml_off, int rank_off, int u) {
    int bh = blockIdx.y;
    int b = bh >> 3, h = bh & 7;
    int tid = threadIdx.x;
    int qi = tid >> 4;
    int kb = tid & 15;
    int ds = kb * 4;
    int row = blockIdx.x * 16 + qi;
    int rank = ((const int*)(g_buf + rank_off))[bh * LL + row];
    size_t idx = ((size_t)b * LL + row) * DM + h * DH + ds;
    if (rank < 0) {
        ushort4 z = {0, 0, 0, 0};
        *(ushort4*)(((u16*)g_buf) + CTX_H + idx) = z;
        *(ushort4*)(((u16*)g_buf) + CTX_L + idx) = z;
        return;
    }
    float m = -3.0e38f;
#pragma unroll
    for (int c = 0; c < NCHUNK; c++)
        m = fmaxf(m, g_buf[pml_off + (((size_t)(bh * NCHUNK + c)) * 512 + rank) * 2]);
    float l = 0.f, O0 = 0.f, O1 = 0.f, O2 = 0.f, O3 = 0.f;
#pragma unroll
    for (int c = 0; c < NCHUNK; c++) {
        size_t rec = ((size_t)(bh * NCHUNK + c)) * 512 + rank;
        const float* pml = g_buf + pml_off + rec * 2;
        float a = __expf(pml[0] - m);
        l += a * pml[1];
        float4 o = *(const float4*)(g_buf + po_off + rec * 64 + ds);
        O0 += a * o.x; O1 += a * o.y; O2 += a * o.z; O3 += a * o.w;
    }
    float inv = 1.0f / l;
    float o0 = O0 * inv, o1 = O1 * inv, o2 = O2 * inv, o3 = O3 * inv;
    ushort4 hv, lv;
    hv.x = f2bf(o0); lv.x = f2bf(o0 - bf2f(hv.x));
    hv.y = f2bf(o1); lv.y = f2bf(o1 - bf2f(hv.y));
    hv.z = f2bf(o2); lv.z = f2bf(o2 - bf2f(hv.z));
    hv.w = f2bf(o3); lv.w = f2bf(o3 - bf2f(hv.w));
    *(ushort4*)(((u16*)g_buf) + CTX_H + idx) = hv;
    *(ushort4*)(((u16*)g_buf) + CTX_L + idx) = lv;
}

// ---------------- orchestration: 20 launches ----------------
extern "C" void kernel_launch(void* const* d_in, const int* in_sizes, int n_in,
                              void* d_out, int out_size, void* d_ws, size_t ws_size,
                              hipStream_t stream) {
    static const int SZ[28] = {
        2097152, 2097152,
        262144, 512, 262144, 512, 262144, 512, 262144, 512,
        262144, 512, 262144, 512, 262144, 512, 262144, 512,
        1048576, 2048, 1048576, 512,
        512, 512, 512, 512, 512, 512
    };
    int OFF[28];
    int cur = 0;
    for (int i = 0; i < 28; i++) { OFF[i] = cur; cur += SZ[i]; }

    P28 ps;
    for (int i = 0; i < 28; i++) ps.p[i] = d_in[i];
    prep_all<<<3072, 256, 0, stream>>>(ps);

    auto select_attend = [&](bool sa) {
        if (sa) kvprep_k<true><<<dim3(32, 16), 256, 0, stream>>>(A_K, A_V, A_PARTK);
        else    kvprep_k<false><<<dim3(32, 16), 256, 0, stream>>>(A_K, A_V, A_PARTK);
        mscore_k<<<dim3(64, 16), 256, 0, stream>>>(A_Q, A_PARTK, A_MS);
        topsel_k<<<dim3(32, 16), 256, 0, stream>>>(A_MS, A_LIST, A_RANK, UU);
        if (sa)
            attn_flash<true><<<896, 256, 0, stream>>>(
                A_Q, KH16, KL16, VTH16, VTL16, A_LIST, A_PO, A_PML, UU);
        else
            attn_flash<false><<<896, 256, 0, stream>>>(
                A_Q, KH16, KL16, VTH16, VTL16, A_LIST, A_PO, A_PML, UU);
        attn_combine<<<dim3(128, 16), 256, 0, stream>>>(A_PO, A_PML, A_RANK, UU);
    };

    // ---- LN1 + self-attention (QKV fused N=1536, sectioned -> A_Q/A_K/A_V) ----
    lnorm_k<<<ROWS, 256, 0, stream>>>(OFF[0], OFF[22], OFF[23], XN_H, XN_L);
    mgemm_k<2, true, true, false, false, false, false><<<dim3(64, 12), 256, 0, stream>>>(
        I3{{XN_H, XN_H, XN_H}}, I3{{1, 1, 1}}, I3{{0, 0, 0}},
        WT_SAQKV, I3{{OFF[3], OFF[5], OFF[7]}}, 0, A_Q, nullptr, ROWS, 1536, 512);
    select_attend(true);
    mgemm_k<1, true, false, false, true, false, false><<<dim3(128, 4), 256, 0, stream>>>(
        I3{{CTX_H, 0, 0}}, I3{{1, 0, 0}}, I3{{0, 0, 0}},
        WT_SAO, I3{{OFF[9], 0, 0}}, OFF[0], OFF[0], nullptr, ROWS, 512, 512);

    // ---- LN2 + cross-attention (caQ+caK+caV fused N=1536, sectioned A: XN/ENC/ENC) ----
    lnorm_k<<<ROWS, 256, 0, stream>>>(OFF[0], OFF[24], OFF[25], XN_H, XN_L);
    mgemm_k<2, true, true, false, false, false, false><<<dim3(64, 12), 256, 0, stream>>>(
        I3{{XN_H, ENC_H, ENC_H}}, I3{{1, 1, 0}}, I3{{0, 1, 0}},
        WT_CAQKV, I3{{OFF[11], OFF[13], OFF[15]}}, 0, A_Q, nullptr, ROWS, 1536, 512);
    select_attend(false);
    mgemm_k<1, false, false, false, true, false, false><<<dim3(128, 4), 256, 0, stream>>>(
        I3{{CTX_H, 0, 0}}, I3{{0, 0, 0}}, I3{{0, 0, 0}},
        WT_CAO, I3{{OFF[17], 0, 0}}, OFF[0], OFF[0], nullptr, ROWS, 512, 512);

    // ---- LN3 + FFN ----
    lnorm_k<<<ROWS, 256, 0, stream>>>(OFF[0], OFF[26], OFF[27], XN_H, XN_L);
    mgemm_k<4, false, false, true, false, false, true><<<dim3(32, 16), 256, 0, stream>>>(
        I3{{XN_H, 0, 0}}, I3{{0, 0, 0}}, I3{{0, 0, 0}},
        WT_W1, I3{{OFF[19], 0, 0}}, 0, AH_H, nullptr, ROWS, 2048, 512);
    mgemm_k<1, false, false, false, true, true, false><<<dim3(128, 4), 256, 0, stream>>>(
        I3{{AH_H, 0, 0}}, I3{{0, 0, 0}}, I3{{0, 0, 0}},
        WT_W2, I3{{OFF[21], 0, 0}}, OFF[0], 0, d_out, ROWS, 512, 2048);
}